// Round 1
// baseline (99.982 us; speedup 1.0000x reference)
//
#include <hip/hip_runtime.h>
#include <math.h>

// Problem constants
#define BATCH 8
#define NVERT 8192
#define NPD   64
#define NCELL 4096          // 64*64 grid cells per batch

// ws layout (in floats unless noted)
#define PARAMS_OFF 0        // kexp2[8], scale[8]
#define TOTALS_OFF 16       // totals[8]
#define KBUF_OFF   32       // 32768 floats (K_H before normalization)
#define PARTIALS_BYTE_OFF ((size_t)1 << 20)   // partials at +1MB

#ifndef M_PI
#define M_PI 3.14159265358979323846
#endif

static __device__ __forceinline__ float fast_exp2(float x) {
#if __has_builtin(__builtin_amdgcn_exp2f)
    return __builtin_amdgcn_exp2f(x);
#else
    return exp2f(x);
#endif
}

// ---------------------------------------------------------------------------
// Kernel 1: per-batch sigma (ddof=1 std per coord, mean of the two, clipped),
// then store kexp2 (for exp2) and the CF*sigma^-2/NV scale. Also zero totals.
// ---------------------------------------------------------------------------
__global__ __launch_bounds__(256) void sigma_kernel(const float* __restrict__ T,
                                                    float* __restrict__ params,
                                                    float* __restrict__ totals) {
    int b = blockIdx.x;
    if (threadIdx.x == 64) totals[b] = 0.0f;   // zero the per-batch total slot

    const float2* Tb = reinterpret_cast<const float2*>(T) + (size_t)b * NVERT;
    double sx = 0.0, sx2 = 0.0, sy = 0.0, sy2 = 0.0;
    for (int j = threadIdx.x; j < NVERT; j += 256) {
        float2 v = Tb[j];
        sx  += (double)v.x;  sx2 += (double)v.x * (double)v.x;
        sy  += (double)v.y;  sy2 += (double)v.y * (double)v.y;
    }
    // wave64 reduce
    for (int off = 32; off; off >>= 1) {
        sx  += __shfl_down(sx,  off);
        sx2 += __shfl_down(sx2, off);
        sy  += __shfl_down(sy,  off);
        sy2 += __shfl_down(sy2, off);
    }
    __shared__ double red[4][4];
    int w = threadIdx.x >> 6, lane = threadIdx.x & 63;
    if (lane == 0) { red[w][0] = sx; red[w][1] = sx2; red[w][2] = sy; red[w][3] = sy2; }
    __syncthreads();
    if (threadIdx.x == 0) {
        double tsx = 0, tsx2 = 0, tsy = 0, tsy2 = 0;
        for (int i = 0; i < 4; ++i) {
            tsx += red[i][0]; tsx2 += red[i][1]; tsy += red[i][2]; tsy2 += red[i][3];
        }
        const double N = (double)NVERT;
        double varx = (tsx2 - tsx * tsx / N) / (N - 1.0);
        double vary = (tsy2 - tsy * tsy / N) / (N - 1.0);
        double sigma = 0.5 * (sqrt(varx) + sqrt(vary));
        const double BD = 1.0 / 63.0;               // (U-L)/(NPD-1)
        if (sigma < BD) sigma = BD;
        // C = NV^(-1/6) = 2^(-13/6)  (since (4/(D+2))^(1/6)=1 for D=2)
        const double C2 = pow(2.0, -13.0 / 3.0);    // C^2
        const double CN = -0.5 / C2;
        const double CF = 1.0 / (2.0 * M_PI * C2);
        double s2 = sigma * sigma;
        params[b]     = (float)(CN / (s2 * 0.69314718055994530942)); // exp2 coefficient
        params[8 + b] = (float)(CF / (s2 * N));                      // CF*sigma^-2 / NV
    }
}

// ---------------------------------------------------------------------------
// Kernel 2: separable KDE main loop. Block = 256 threads (16x16), each thread
// owns a 4x4 cell tile of the 64x64 grid. Split-K over vertices across blocks.
// Per group of G=16 vertices: stage ex[g][0..63], ey[g][0..63] in LDS, then
// 16 FMAs per vertex per thread from two ds_read_b128.
// ---------------------------------------------------------------------------
#define G 16

__global__ __launch_bounds__(256) void kde_main(const float* __restrict__ T,
                                                const float* __restrict__ params,
                                                float* __restrict__ partials,
                                                int splits, int jpb) {
    int b  = blockIdx.x / splits;
    int sp = blockIdx.x % splits;
    int j0 = sp * jpb;

    __shared__ float es[G][128];     // [g][0..63]=ex, [g][64..127]=ey
    __shared__ float2 tj[1024];      // vertex chunk (jpb <= 1024)

    float kexp2 = params[b];
    const float2* Tb = reinterpret_cast<const float2*>(T) + (size_t)b * NVERT + j0;
    for (int r = threadIdx.x; r < jpb; r += 256) tj[r] = Tb[r];

    int tx = threadIdx.x & 15;       // gx block: cells tx*4 .. tx*4+3
    int ty = threadIdx.x >> 4;       // gy block: cells ty*4 .. ty*4+3

    float acc[4][4];
#pragma unroll
    for (int i = 0; i < 4; ++i)
#pragma unroll
        for (int j = 0; j < 4; ++j) acc[i][j] = 0.0f;

    for (int jg = 0; jg < jpb; jg += G) {
        __syncthreads();             // protects es (prev reads) and tj (first iter)
        // stage G*128 = 2048 exp values: 8 per thread, lane-contiguous writes
#pragma unroll
        for (int r = 0; r < 8; ++r) {
            int idx = r * 256 + threadIdx.x;
            int g = idx >> 7, c = idx & 127;
            float2 t2 = tj[jg + g];
            float tv = (c < 64) ? t2.x : t2.y;
            float d = (float)(c & 63) * (1.0f / 63.0f) - tv;
            es[g][c] = fast_exp2(kexp2 * d * d);
        }
        __syncthreads();
#pragma unroll
        for (int g = 0; g < G; ++g) {
            float4 ex = *reinterpret_cast<const float4*>(&es[g][tx * 4]);
            float4 ey = *reinterpret_cast<const float4*>(&es[g][64 + ty * 4]);
            acc[0][0] += ex.x * ey.x; acc[0][1] += ex.x * ey.y;
            acc[0][2] += ex.x * ey.z; acc[0][3] += ex.x * ey.w;
            acc[1][0] += ex.y * ey.x; acc[1][1] += ex.y * ey.y;
            acc[1][2] += ex.y * ey.z; acc[1][3] += ex.y * ey.w;
            acc[2][0] += ex.z * ey.x; acc[2][1] += ex.z * ey.y;
            acc[2][2] += ex.z * ey.z; acc[2][3] += ex.z * ey.w;
            acc[3][0] += ex.w * ey.x; acc[3][1] += ex.w * ey.y;
            acc[3][2] += ex.w * ey.z; acc[3][3] += ex.w * ey.w;
        }
    }

    float* dst = partials + (size_t)blockIdx.x * NCELL;
#pragma unroll
    for (int i = 0; i < 4; ++i) {
        float4 v = make_float4(acc[i][0], acc[i][1], acc[i][2], acc[i][3]);
        *reinterpret_cast<float4*>(&dst[(tx * 4 + i) * 64 + ty * 4]) = v;
    }
}

// ---------------------------------------------------------------------------
// Kernel 3: sum split-K partials -> K_H (scaled), accumulate per-batch totals.
// Grid = BATCH*16 blocks x 256 threads: exactly one thread per cell.
// ---------------------------------------------------------------------------
__global__ __launch_bounds__(256) void reduce_kernel(const float* __restrict__ partials,
                                                     const float* __restrict__ params,
                                                     float* __restrict__ Kbuf,
                                                     float* __restrict__ totals,
                                                     int splits) {
    int b    = blockIdx.x >> 4;
    int cell = ((blockIdx.x & 15) << 8) + threadIdx.x;
    const float* p = partials + (size_t)b * splits * NCELL + cell;
    float s = 0.0f;
    for (int k = 0; k < splits; ++k) s += p[(size_t)k * NCELL];
    float K = s * params[8 + b];
    Kbuf[b * NCELL + cell] = K;

    // block-sum K -> atomic into totals[b]
    float v = K;
    for (int off = 32; off; off >>= 1) v += __shfl_down(v, off);
    __shared__ float r4[4];
    int w = threadIdx.x >> 6, lane = threadIdx.x & 63;
    if (lane == 0) r4[w] = v;
    __syncthreads();
    if (threadIdx.x == 0) atomicAdd(&totals[b], r4[0] + r4[1] + r4[2] + r4[3]);
}

// ---------------------------------------------------------------------------
// Kernel 4: normalize.
// ---------------------------------------------------------------------------
__global__ __launch_bounds__(256) void norm_kernel(const float* __restrict__ Kbuf,
                                                   const float* __restrict__ totals,
                                                   float* __restrict__ out) {
    int b    = blockIdx.x >> 4;
    int cell = ((blockIdx.x & 15) << 8) + threadIdx.x;
    float denom = totals[b];
    denom = fmaxf(denom, 1e-5f);
    out[b * NCELL + cell] = Kbuf[b * NCELL + cell] / denom;
}

// ---------------------------------------------------------------------------
extern "C" void kernel_launch(void* const* d_in, const int* in_sizes, int n_in,
                              void* d_out, int out_size, void* d_ws, size_t ws_size,
                              hipStream_t stream) {
    const float* T = (const float*)d_in[0];   // [B, NV, 2] f32
    // d_in[1] (S) is a deterministic 64x64 meshgrid in [0,1]^2 — recomputed inline.

    float* ws      = (float*)d_ws;
    float* params  = ws + PARAMS_OFF;
    float* totals  = ws + TOTALS_OFF;
    float* Kbuf    = ws + KBUF_OFF;
    float* partials = (float*)((char*)d_ws + PARTIALS_BYTE_OFF);

    int splits = 64;   // blocks per batch for split-K
    while (splits > 8 &&
           PARTIALS_BYTE_OFF + (size_t)splits * BATCH * NCELL * sizeof(float) > ws_size)
        splits >>= 1;
    int jpb = NVERT / splits;

    sigma_kernel<<<BATCH, 256, 0, stream>>>(T, params, totals);
    kde_main<<<BATCH * splits, 256, 0, stream>>>(T, params, partials, splits, jpb);
    reduce_kernel<<<BATCH * 16, 256, 0, stream>>>(partials, params, Kbuf, totals, splits);
    norm_kernel<<<BATCH * 16, 256, 0, stream>>>(Kbuf, totals, (float*)d_out);
}

// Round 3
// 80.312 us; speedup vs baseline: 1.2449x; 1.2449x over previous
//
#include <hip/hip_runtime.h>
#include <math.h>

// Problem constants
#define BATCH 8
#define NVERT 8192
#define NPD   64
#define NCELL 4096            // 64*64 grid cells per batch
#define SPLITS 64             // split-K blocks per batch
#define JPB   (NVERT / SPLITS) // 128 vertices per block
#define G     16              // vertex group per staging round

#ifndef M_PI
#define M_PI 3.14159265358979323846
#endif

// ws layout (floats)
#define PARAMS_OFF   0        // scale[8]
#define TOTPART_OFF  16       // totpart[512]
#define PARTIALS_OFF 1024     // 512 * 4096 floats = 8 MB

static __device__ __forceinline__ float fast_exp2(float x) {
#if __has_builtin(__builtin_amdgcn_exp2f)
    return __builtin_amdgcn_exp2f(x);
#else
    return exp2f(x);
#endif
}

// ---------------------------------------------------------------------------
// Kernel A: fused sigma + separable KDE + per-block total.
// Grid = BATCH*SPLITS = 512 blocks x 256 threads. Each block:
//   phase 0: scan full batch T (fp32 sums -> sigma, ddof=1), stash its own
//            JPB-vertex slice in LDS along the way.
//   phase 1: per 16-vertex group, stage ex/ey rows (2048 exp2) in LDS, then
//            each thread accumulates a 4x4 cell tile (16 FMA/vertex).
//   phase 2: write 64x64 partial + block-total (= sum of all accs) slot.
// ---------------------------------------------------------------------------
__global__ __launch_bounds__(256) void kde_kernel(const float* __restrict__ T,
                                                  float* __restrict__ params,
                                                  float* __restrict__ totpart,
                                                  float* __restrict__ partials) {
    const int b   = blockIdx.x >> 6;           // / SPLITS
    const int sp  = blockIdx.x & (SPLITS - 1);
    const int j0  = sp * JPB;
    const int tid = threadIdx.x;

    __shared__ float  es[G][128];   // [g][0..63]=ex row, [g][64..127]=ey row
    __shared__ float2 tj[JPB];      // this block's vertex slice
    __shared__ float  red[4][4];
    __shared__ float  bcast[2];     // kexp2, scale

    // ---- phase 0: sigma over the full batch (redundant per block) ----
    const float2* Tb = reinterpret_cast<const float2*>(T) + (size_t)b * NVERT;
    float sx = 0.f, sx2 = 0.f, sy = 0.f, sy2 = 0.f;
    for (int j = tid; j < NVERT; j += 256) {
        float2 v = Tb[j];
        sx += v.x; sx2 = fmaf(v.x, v.x, sx2);
        sy += v.y; sy2 = fmaf(v.y, v.y, sy2);
        int local = j - j0;
        if ((unsigned)local < (unsigned)JPB) tj[local] = v;  // each slice elem hit once
    }
    for (int off = 32; off; off >>= 1) {
        sx  += __shfl_down(sx,  off);  sx2 += __shfl_down(sx2, off);
        sy  += __shfl_down(sy,  off);  sy2 += __shfl_down(sy2, off);
    }
    const int w = tid >> 6, lane = tid & 63;
    if (lane == 0) { red[w][0] = sx; red[w][1] = sx2; red[w][2] = sy; red[w][3] = sy2; }
    __syncthreads();
    if (tid == 0) {
        double tsx = 0, tsx2 = 0, tsy = 0, tsy2 = 0;
        for (int i = 0; i < 4; ++i) {
            tsx += red[i][0]; tsx2 += red[i][1]; tsy += red[i][2]; tsy2 += red[i][3];
        }
        const double N = (double)NVERT;
        double varx = (tsx2 - tsx * tsx / N) / (N - 1.0);
        double vary = (tsy2 - tsy * tsy / N) / (N - 1.0);
        double sigma = 0.5 * (sqrt(varx) + sqrt(vary));
        const double BD = 1.0 / 63.0;
        if (sigma < BD) sigma = BD;
        const double C2 = pow(2.0, -13.0 / 3.0);   // C^2, C = NV^(-1/6)
        double s2 = sigma * sigma;
        bcast[0] = (float)(-0.5 / C2 / (s2 * 0.69314718055994530942)); // exp2 coeff
        bcast[1] = (float)(1.0 / (2.0 * M_PI * C2) / (s2 * N));        // CF*sigma^-2/NV
        if (sp == 0) params[b] = bcast[1];
    }
    __syncthreads();
    const float kexp2 = bcast[0];

    // ---- phase 1: separable outer-product accumulation ----
    const int tx = tid & 15;    // x-cells tx*4..tx*4+3
    const int ty = tid >> 4;    // y-cells ty*4..ty*4+3
    float acc[4][4];
#pragma unroll
    for (int i = 0; i < 4; ++i)
#pragma unroll
        for (int j = 0; j < 4; ++j) acc[i][j] = 0.0f;

    for (int jg = 0; jg < JPB; jg += G) {
        __syncthreads();               // protect es from previous group's readers
#pragma unroll
        for (int r = 0; r < 8; ++r) {  // 2048 exps, 8 per thread, bank-sequential
            int idx = r * 256 + tid;
            int g = idx >> 7, c = idx & 127;
            float2 t2 = tj[jg + g];
            float tv = (c < 64) ? t2.x : t2.y;
            float d = (float)(c & 63) * (1.0f / 63.0f) - tv;
            es[g][c] = fast_exp2(kexp2 * d * d);
        }
        __syncthreads();
#pragma unroll
        for (int g = 0; g < G; ++g) {
            float4 ex = *reinterpret_cast<const float4*>(&es[g][tx * 4]);
            float4 ey = *reinterpret_cast<const float4*>(&es[g][64 + ty * 4]);
            acc[0][0] += ex.x * ey.x; acc[0][1] += ex.x * ey.y;
            acc[0][2] += ex.x * ey.z; acc[0][3] += ex.x * ey.w;
            acc[1][0] += ex.y * ey.x; acc[1][1] += ex.y * ey.y;
            acc[1][2] += ex.y * ey.z; acc[1][3] += ex.y * ey.w;
            acc[2][0] += ex.z * ey.x; acc[2][1] += ex.z * ey.y;
            acc[2][2] += ex.z * ey.z; acc[2][3] += ex.z * ey.w;
            acc[3][0] += ex.w * ey.x; acc[3][1] += ex.w * ey.y;
            acc[3][2] += ex.w * ey.z; acc[3][3] += ex.w * ey.w;
        }
    }

    // ---- phase 2: write partials + block total (no atomics, no zero-init) ----
    float* dst = partials + (size_t)blockIdx.x * NCELL;
    float tsum = 0.f;
#pragma unroll
    for (int i = 0; i < 4; ++i) {
        float4 v = make_float4(acc[i][0], acc[i][1], acc[i][2], acc[i][3]);
        *reinterpret_cast<float4*>(&dst[(tx * 4 + i) * 64 + ty * 4]) = v;
        tsum += (acc[i][0] + acc[i][1]) + (acc[i][2] + acc[i][3]);
    }
    for (int off = 32; off; off >>= 1) tsum += __shfl_down(tsum, off);
    __syncthreads();                   // red[] reuse
    if (lane == 0) red[w][0] = tsum;
    __syncthreads();
    if (tid == 0) totpart[blockIdx.x] = (red[0][0] + red[1][0]) + (red[2][0] + red[3][0]);
}

// ---------------------------------------------------------------------------
// Kernel B: sum split-K partials, batch total from totpart slots, scale,
// normalize, write out. Grid = BATCH*16 blocks x 256 threads (1 thread/cell).
// ---------------------------------------------------------------------------
__global__ __launch_bounds__(256) void finish_kernel(const float* __restrict__ partials,
                                                     const float* __restrict__ totpart,
                                                     const float* __restrict__ params,
                                                     float* __restrict__ out) {
    const int b    = blockIdx.x >> 4;
    const int cell = ((blockIdx.x & 15) << 8) + threadIdx.x;
    const float* p = partials + (size_t)(b * SPLITS) * NCELL + cell;
    float s0 = 0.f, s1 = 0.f, s2 = 0.f, s3 = 0.f;
#pragma unroll
    for (int k = 0; k < SPLITS; k += 4) {        // 4 chains to hide L2 latency
        s0 += p[(size_t)(k + 0) * NCELL];
        s1 += p[(size_t)(k + 1) * NCELL];
        s2 += p[(size_t)(k + 2) * NCELL];
        s3 += p[(size_t)(k + 3) * NCELL];
    }
    float s = (s0 + s1) + (s2 + s3);

    __shared__ float tot_s;
    if (threadIdx.x < 64) {
        float v = totpart[(b << 6) + threadIdx.x];
        for (int off = 32; off; off >>= 1) v += __shfl_down(v, off);
        if (threadIdx.x == 0) tot_s = v;
    }
    __syncthreads();
    const float scale = params[b];
    const float denom = fmaxf(tot_s * scale, 1e-5f);
    out[b * NCELL + cell] = (s * scale) / denom;
}

// ---------------------------------------------------------------------------
extern "C" void kernel_launch(void* const* d_in, const int* in_sizes, int n_in,
                              void* d_out, int out_size, void* d_ws, size_t ws_size,
                              hipStream_t stream) {
    const float* T = (const float*)d_in[0];   // [B, NV, 2] f32
    // d_in[1] (S) is a deterministic 64x64 meshgrid in [0,1]^2 — derived inline.

    float* ws       = (float*)d_ws;
    float* params   = ws + PARAMS_OFF;
    float* totpart  = ws + TOTPART_OFF;
    float* partials = ws + PARTIALS_OFF;

    kde_kernel<<<BATCH * SPLITS, 256, 0, stream>>>(T, params, totpart, partials);
    finish_kernel<<<BATCH * 16, 256, 0, stream>>>(partials, totpart, params, (float*)d_out);
}